// Round 4
// baseline (496.734 us; speedup 1.0000x reference)
//
#include <hip/hip_runtime.h>
#include <float.h>
#include <math.h>

#define HH 224
#define WW 224
#define PLANE (HH*WW)
#define FRAME (3*HH*WW)   // 150528
#define LFR 64            // frames per batch
#define NP 63             // pairs per batch
#define NB 8              // batch
#define NM 16             // MAX_NUM_FRAME
#define EPSV 1e-6f

#define RSLAB 32            // output rows per slab
#define NSLAB (HH / RSLAB)  // 7
#define DROWS (RSLAB + 6)   // 38 chansum rows incl. halo
#define LDW 232             // padded LDS row: 4 zero | 224 data | 4 zero
#define NQ 56               // float4 quads per data row
#define UNITS3 (DROWS * NQ) // 2128 load units per frame-slab
#define KP 7                // pairs per block
#define NG (NP / KP)        // 9 pair-groups per batch
#define FPB (KP + 1)        // 8 frames per block

// ---------------- Stage 1: per-frame box map, per-pair diff score ----------------
// W_l = box7x7( sum_ch x[b,l] )  (zero-padded).  Since conv is linear:
// diff_score contribution = | w*(W_l - W_{l+1}) + eps |.
// One block per (slab, b, pair-group). 8 frames staged once each (not twice).
__global__ __launch_bounds__(256) void diff_kernel(
    const float* __restrict__ x, const float* __restrict__ cw,
    float* __restrict__ dsp)
{
    const int slab = blockIdx.x;           // 0..6
    const int bg   = blockIdx.y;           // b*NG + g
    const int b    = bg / NG;
    const int g    = bg - b * NG;
    const int l0   = g * KP;               // first pair / first frame of group
    const float w  = cw[0];

    const int rBase = slab * RSLAB - 3;    // global row of local chansum-row 0

    __shared__ float Dl[DROWS][LDW];       // 35.3 KB chansum slab (one frame)
    __shared__ float red[KP][4];

    const int tid = threadIdx.x;

    // Zero the 4-col pads (written once; Phase A never touches cols 0..3 / 228..231).
    if (tid < 2 * DROWS) {
        const int r = tid >> 1;
        const int col = (tid & 1) ? (LDW - 4) : 0;
        *(float4*)&Dl[r][col] = make_float4(0.f, 0.f, 0.f, 0.f);
    }

    float Wprev[RSLAB];

    #pragma unroll 1
    for (int f = 0; f < FPB; ++f) {
        // ---- Phase A: stage chansum(frame l0+f) slab into LDS (float4, flat loop)
        const float4* p = (const float4*)(x + (size_t)(b * LFR + l0 + f) * FRAME);
        for (int u = tid; u < UNITS3; u += 256) {
            const int r  = u / NQ;
            const int cq = u - r * NQ;
            const int gr = rBase + r;
            float4 v = make_float4(0.f, 0.f, 0.f, 0.f);
            if (gr >= 0 && gr < HH) {
                const int off = (gr * WW + cq * 4) >> 2;
                const float4 a0 = p[off];
                const float4 a1 = p[off + PLANE/4];
                const float4 a2 = p[off + 2*PLANE/4];
                v.x = a0.x + a1.x + a2.x;
                v.y = a0.y + a1.y + a2.y;
                v.z = a0.z + a1.z + a2.z;
                v.w = a0.w + a1.w + a2.w;
            }
            *(float4*)&Dl[r][4 + cq * 4] = v;
        }
        __syncthreads();

        // ---- Phase B: this frame's W column (7x7 box) + pair accumulation
        float pacc = 0.f;
        if (tid < WW) {
            float Hrow[DROWS];
            #pragma unroll
            for (int r = 0; r < DROWS; ++r) {
                float h = Dl[r][tid + 1];
                #pragma unroll
                for (int k = 2; k <= 7; ++k) h += Dl[r][tid + k];
                Hrow[r] = h;
            }
            #pragma unroll
            for (int i = 0; i < RSLAB; ++i) {
                const float Wc = Hrow[i] + Hrow[i+1] + Hrow[i+2] + Hrow[i+3]
                               + Hrow[i+4] + Hrow[i+5] + Hrow[i+6];
                if (f > 0) pacc += fabsf(w * (Wprev[i] - Wc) + EPSV);
                Wprev[i] = Wc;
            }
        }
        if (f > 0) {
            #pragma unroll
            for (int off = 32; off >= 1; off >>= 1)
                pacc += __shfl_down(pacc, off, 64);
            if ((tid & 63) == 0) red[f - 1][tid >> 6] = pacc;
        }
        __syncthreads();   // red written & Dl reads done before next overwrite
    }

    if (tid < KP) {
        dsp[(b * NP + l0 + tid) * NSLAB + slab] =
            red[tid][0] + red[tid][1] + red[tid][2] + red[tid][3];
    }
}

// ---------------- Stage 2: dsp -> cumsum -> argmin indices ----------------
__global__ __launch_bounds__(64) void select_kernel(
    const float* __restrict__ dsp, int* __restrict__ idx)
{
    const int b = blockIdx.x;
    const int lane = threadIdx.x;
    float v = 0.f;
    if (lane < NP) {
        float s = 0.f;
        #pragma unroll
        for (int k = 0; k < NSLAB; ++k) s += dsp[(b * NP + lane) * NSLAB + k];
        v = sqrtf(s);                    // power(diff_score, 0.5)
    }

    float tot = v;
    #pragma unroll
    for (int off = 1; off < 64; off <<= 1)
        tot += __shfl_xor(tot, off, 64);

    float scan = v;
    #pragma unroll
    for (int off = 1; off < 64; off <<= 1) {
        float t = __shfl_up(scan, off, 64);
        if (lane >= off) scan += t;
    }
    const float cum = scan / tot;

    const float interval = 1.0f / (NM - 1);
    for (int m = 0; m < NM; ++m) {
        const float target = (float)m * interval;
        float bv = (lane < NP) ? fabsf(cum - target) : FLT_MAX;
        int bi = lane;
        #pragma unroll
        for (int off = 1; off < 64; off <<= 1) {
            float ov = __shfl_xor(bv, off, 64);
            int oi = __shfl_xor(bi, off, 64);
            if (ov < bv || (ov == bv && oi < bi)) { bv = ov; bi = oi; }
        }
        if (lane == 0) idx[b * NM + m] = bi;
    }
}

// ---------------- Stage 3: gather selected frames ----------------
// 7 float4 per thread; FRAME/4 = 37632 = 21 * 256 * 7.
__global__ __launch_bounds__(256) void gather_kernel(
    const float* __restrict__ x, const int* __restrict__ idx,
    float* __restrict__ out)
{
    const int f = blockIdx.y;            // b*NM + m, 0..127
    const int b = f >> 4;
    const int id = idx[f];
    const float4* src = (const float4*)(x + (size_t)(b * LFR + id) * FRAME);
    float4* dst = (float4*)(out + (size_t)f * FRAME);
    const int i = blockIdx.x * 256 + threadIdx.x;
    #pragma unroll
    for (int k = 0; k < 7; ++k)
        dst[i + k * (21 * 256)] = src[i + k * (21 * 256)];
}

extern "C" void kernel_launch(void* const* d_in, const int* in_sizes, int n_in,
                              void* d_out, int out_size, void* d_ws, size_t ws_size,
                              hipStream_t stream) {
    const float* x  = (const float*)d_in[0];
    const float* cw = (const float*)d_in[1];
    // conv_b is identically zero and cancels in the pair difference.
    float* dsp = (float*)d_ws;                       // 504*7 floats
    int*   idx = (int*)((char*)d_ws + 16384);        // 128 ints

    hipLaunchKernelGGL(diff_kernel, dim3(NSLAB, NB * NG), dim3(256), 0, stream,
                       x, cw, dsp);
    hipLaunchKernelGGL(select_kernel, dim3(NB), dim3(64), 0, stream, dsp, idx);
    hipLaunchKernelGGL(gather_kernel, dim3(21, NB * NM), dim3(256), 0, stream,
                       x, idx, (float*)d_out);
}